// Round 5
// baseline (49.497 us; speedup 1.0000x reference)
//
#include <hip/hip_runtime.h>

typedef _Float16 f16;
typedef _Float16 f16x2 __attribute__((ext_vector_type(2)));
typedef _Float16 f16x4 __attribute__((ext_vector_type(4)));
typedef float    f32x4 __attribute__((ext_vector_type(4)));
typedef unsigned int u32;
typedef unsigned int u32x2v __attribute__((ext_vector_type(2)));

#define NS 2048
#define NH 16
#define NDK 8
#define NE 128
#define CHUNK 512
#define NCHUNK 4
// log2(e)/sqrt(8): exp(dot/sqrt(8)) == exp2(dot * CSCALE)
#define CSCALE 0.51006972f

__device__ __forceinline__ float fexp2(float v){
#if __has_builtin(__builtin_amdgcn_exp2f)
  return __builtin_amdgcn_exp2f(v);
#else
  return exp2f(v);
#endif
}

__device__ __forceinline__ f16x2 pkrtz(float a, float b){
  return __builtin_bit_cast(f16x2, __builtin_amdgcn_cvt_pkrtz(a, b));
}

__device__ __forceinline__ float fdot2a(f16x2 a, f16x2 b, float c){
#if __has_builtin(__builtin_amdgcn_fdot2)
  return __builtin_amdgcn_fdot2(a, b, c, false);
#else
  return c + (float)a[0]*(float)b[0] + (float)a[1]*(float)b[1];
#endif
}

// ---------------------------------------------------------------------------
// Attention: grid 1024 = 64 (b,h) x 16 q-chunks of 128 rows. Block 512 thr
// (8 waves x 16 q-rows). LDS ~17KB -> 4 blocks/CU = 32 waves/CU = 8/SIMD.
// K/V streamed in 512-key chunks: stage(cos+pack) -> bar -> compute -> bar.
// Next chunk's global loads issued before compute (latency hidden).
// Inner loop (per 16-key tile): S^T = mfma16x16x16f16(A=K, B=Q*CSCALE),
// P = exp2(S^T) -> pkrtz -> B of out^T += mfma(A=V^T, B=P^T).
// V^T rows for lanes c>=8 come from a 1KB LDS "ones" region via the base
// pointer (no cndmask) -> accumulator row 8 = softmax denominator.
// All LDS reads use per-lane base + immediate offsets: zero addr VALU.
// ---------------------------------------------------------------------------
__global__ __launch_bounds__(512, 8) void qattn(const float* __restrict__ x,
                                                const float* __restrict__ theta,
                                                float* __restrict__ out){
  __shared__ __align__(16) uint4 Kc[CHUNK];              // 8KB: [key][8 f16]
  __shared__ __align__(16) unsigned short Vc[8*CHUNK];   // 8KB: V^T swizzled
  __shared__ __align__(16) uint2 Ones[128];              // 1KB of f16 1.0

  const int bid  = blockIdx.x;
  const int bh   = bid >> 4;        // 0..63
  const int qc   = bid & 15;        // q-chunk of 128 rows
  const int b    = bh >> 4;
  const int h    = bh & 15;
  const int tid  = threadIdx.x;
  const int lane = tid & 63;
  const int w    = tid >> 6;        // wave 0..7
  const int c    = lane & 15;
  const int grp  = lane >> 4;       // 0..3
  const int g1   = grp & 1;
  const bool lo32 = lane < 32;
  const int dvx  = c & 7;

  const float* xbh = x + (size_t)(b*NS*NH + h)*NDK;   // row s at +s*128

  // ones region init (FULL 1KB = 64 uint4; R4 bug: only 32 were written)
  if(tid < 64){
    uint4 o; o.x = o.y = o.z = o.w = 0x3C003C00u;
    ((uint4*)Ones)[tid] = o;
  }

  // ---- per-wave Q fragment: rows qc*128 + w*16 + c, dims 4*g1..4*g1+3 ----
  const int qrow = qc*128 + w*16 + c;
  const float4 th4 = ((const float4*)theta)[g1];
  const float4 xq = *(const float4*)(xbh + (size_t)qrow*(NH*NDK) + g1*4);
  f16x2 qa = pkrtz(__cosf(xq.x+th4.x)*CSCALE, __cosf(xq.y+th4.y)*CSCALE);
  f16x2 qb = pkrtz(__cosf(xq.z+th4.z)*CSCALE, __cosf(xq.w+th4.w)*CSCALE);
  u32x2v qu = { lo32 ? __builtin_bit_cast(u32, qa) : 0u,
                lo32 ? __builtin_bit_cast(u32, qb) : 0u };
  const f16x4 qf = __builtin_bit_cast(f16x4, qu);

  // ---- per-lane LDS read bases (constant across chunks; imm offsets only) --
  const uint2* kp  = (const uint2*)Kc + c*2 + g1;            // + ktc*32
  const uint2* vp0 = (c < 8) ? ((const uint2*)Vc + dvx*128 + ((grp  ) ^ dvx))
                             : Ones;                          // + m*8
  const uint2* vp1 = (c < 8) ? ((const uint2*)Vc + dvx*128 + ((4+grp) ^ dvx))
                             : Ones;                          // + m*8

  const float4 thA = ((const float4*)theta)[0];
  const float4 thB = ((const float4*)theta)[1];

  const f32x4 z4 = {0.f,0.f,0.f,0.f};
  f32x4 acc0 = z4, acc1 = z4;

  // initial prefetch: chunk 0, one key-row per thread
  float4 rx0 = *(const float4*)(xbh + (size_t)tid*(NH*NDK));
  float4 rx1 = *(const float4*)(xbh + (size_t)tid*(NH*NDK) + 4);

  for(int cc = 0; cc < NCHUNK; ++cc){
    // ---- stage chunk cc (key = cc*512 + tid) ----
    union { f16 hh[8]; uint4 u; } pk;
    pk.hh[0] = (f16)__cosf(rx0.x + thA.x);
    pk.hh[1] = (f16)__cosf(rx0.y + thA.y);
    pk.hh[2] = (f16)__cosf(rx0.z + thA.z);
    pk.hh[3] = (f16)__cosf(rx0.w + thA.w);
    pk.hh[4] = (f16)__cosf(rx1.x + thB.x);
    pk.hh[5] = (f16)__cosf(rx1.y + thB.y);
    pk.hh[6] = (f16)__cosf(rx1.z + thB.z);
    pk.hh[7] = (f16)__cosf(rx1.w + thB.w);
    Kc[tid] = pk.u;
    {
      int sb = tid >> 2, sl = tid & 3;
      #pragma unroll
      for(int d = 0; d < 8; ++d)
        Vc[d*CHUNK + (((sb ^ d) << 2) | sl)] =
            __builtin_bit_cast(unsigned short, pk.hh[d]);
    }
    __syncthreads();

    // prefetch next chunk while computing this one
    if(cc + 1 < NCHUNK){
      const float* nx = xbh + (size_t)((cc+1)*CHUNK + tid)*(NH*NDK);
      rx0 = *(const float4*)(nx);
      rx1 = *(const float4*)(nx + 4);
    }

    // ---- compute 32 key-tiles of 16 ----
    #pragma unroll
    for(int m = 0; m < 16; ++m){
      {
        uint2 ka = kp[(2*m+0)*32];
        uint2 va = vp0[m*8];
        f16x4 kf = __builtin_bit_cast(f16x4, ka);
        f16x4 vf = __builtin_bit_cast(f16x4, va);
        f32x4 st = __builtin_amdgcn_mfma_f32_16x16x16f16(kf, qf, z4, 0, 0, 0);
        f16x2 plo = pkrtz(fexp2(st[0]), fexp2(st[1]));
        f16x2 phi = pkrtz(fexp2(st[2]), fexp2(st[3]));
        u32x2v pu = { __builtin_bit_cast(u32, plo), __builtin_bit_cast(u32, phi) };
        f16x4 pf = __builtin_bit_cast(f16x4, pu);
        acc0 = __builtin_amdgcn_mfma_f32_16x16x16f16(vf, pf, acc0, 0, 0, 0);
      }
      {
        uint2 ka = kp[(2*m+1)*32];
        uint2 va = vp1[m*8];
        f16x4 kf = __builtin_bit_cast(f16x4, ka);
        f16x4 vf = __builtin_bit_cast(f16x4, va);
        f32x4 st = __builtin_amdgcn_mfma_f32_16x16x16f16(kf, qf, z4, 0, 0, 0);
        f16x2 plo = pkrtz(fexp2(st[0]), fexp2(st[1]));
        f16x2 phi = pkrtz(fexp2(st[2]), fexp2(st[3]));
        u32x2v pu = { __builtin_bit_cast(u32, plo), __builtin_bit_cast(u32, phi) };
        f16x4 pf = __builtin_bit_cast(f16x4, pu);
        acc1 = __builtin_amdgcn_mfma_f32_16x16x16f16(vf, pf, acc1, 0, 0, 0);
      }
    }

    if(cc + 1 < NCHUNK) __syncthreads();   // before overwriting Kc/Vc
  }

  // ---- epilogue: row 8 of acc = denominator for column q=c ----
  f32x4 accT;
  accT[0] = acc0[0]+acc1[0]; accT[1] = acc0[1]+acc1[1];
  accT[2] = acc0[2]+acc1[2]; accT[3] = acc0[3]+acc1[3];
  float den = __shfl(accT[0], 32 + c, 64);
  if(lo32){
    float inv = 1.0f / den;
    float4 o;
    o.x = accT[0]*inv; o.y = accT[1]*inv; o.z = accT[2]*inv; o.w = accT[3]*inv;
    *(float4*)(out + ((size_t)(b*NS + qrow)*NH + h)*NDK + grp*4) = o;
  }
}

// ---------------------------------------------------------------------------
// Combine: out = attn @ W^T + bias, in-place on d_out (unchanged from R3).
// ---------------------------------------------------------------------------
__global__ __launch_bounds__(256) void qcomb(const float* __restrict__ W,
                                             const float* __restrict__ bias,
                                             float* __restrict__ io){
  __shared__ __align__(16) u32 Wt[64*132];
  __shared__ __align__(16) u32 A2[32*65];
  const int tid = threadIdx.x;
  const size_t row0 = (size_t)blockIdx.x * 32;

  #pragma unroll
  for(int i=0;i<32;++i){
    int g = tid + 256*i;
    int j = g >> 6, e2 = g & 63;
    const float* wp = W + (size_t)j*NE + 2*e2;
    f16x2 wv = pkrtz(wp[0], wp[1]);
    Wt[e2*132 + j] = __builtin_bit_cast(u32, wv);
  }
  #pragma unroll
  for(int i=0;i<8;++i){
    int g = tid + 256*i;
    int r = g >> 6, e2 = g & 63;
    const float* ap = io + (row0 + r)*NE + 2*e2;
    f16x2 av = pkrtz(ap[0], ap[1]);
    A2[r*65 + e2] = __builtin_bit_cast(u32, av);
  }
  __syncthreads();

  const int tr = tid >> 4, tc = tid & 15;
  float acc0[8] = {0,0,0,0,0,0,0,0};
  float acc1[8] = {0,0,0,0,0,0,0,0};
  for(int e2=0; e2<64; ++e2){
    f16x2 a0 = __builtin_bit_cast(f16x2, A2[tr*65 + e2]);
    f16x2 a1 = __builtin_bit_cast(f16x2, A2[(tr+16)*65 + e2]);
    const u32* wr = &Wt[e2*132 + tc*8];
    #pragma unroll
    for(int cj=0; cj<8; ++cj){
      f16x2 wv = __builtin_bit_cast(f16x2, wr[cj]);
      acc0[cj] = fdot2a(a0, wv, acc0[cj]);
      acc1[cj] = fdot2a(a1, wv, acc1[cj]);
    }
  }

  float4 b0 = *(const float4*)(bias + tc*8);
  float4 b1 = *(const float4*)(bias + tc*8 + 4);
  float* o0 = io + (row0 + tr)*NE + tc*8;
  float* o1 = io + (row0 + tr + 16)*NE + tc*8;
  float4 v;
  v.x = acc0[0]+b0.x; v.y = acc0[1]+b0.y; v.z = acc0[2]+b0.z; v.w = acc0[3]+b0.w;
  *(float4*)(o0) = v;
  v.x = acc0[4]+b1.x; v.y = acc0[5]+b1.y; v.z = acc0[6]+b1.z; v.w = acc0[7]+b1.w;
  *(float4*)(o0+4) = v;
  v.x = acc1[0]+b0.x; v.y = acc1[1]+b0.y; v.z = acc1[2]+b0.z; v.w = acc1[3]+b0.w;
  *(float4*)(o1) = v;
  v.x = acc1[4]+b1.x; v.y = acc1[5]+b1.y; v.z = acc1[6]+b1.z; v.w = acc1[7]+b1.w;
  *(float4*)(o1+4) = v;
}

extern "C" void kernel_launch(void* const* d_in, const int* in_sizes, int n_in,
                              void* d_out, int out_size, void* d_ws, size_t ws_size,
                              hipStream_t stream) {
  (void)in_sizes; (void)n_in; (void)out_size; (void)d_ws; (void)ws_size;
  const float* x     = (const float*)d_in[0];
  const float* theta = (const float*)d_in[1];
  const float* W     = (const float*)d_in[2];
  const float* bias  = (const float*)d_in[3];
  float* out = (float*)d_out;

  qattn<<<1024, 512, 0, stream>>>(x, theta, out);
  qcomb<<<256, 256, 0, stream>>>(W, bias, out);
}